// Round 1
// baseline (227.842 us; speedup 1.0000x reference)
//
#include <hip/hip_runtime.h>

// MLSA-style multi-stage time-varying FIR.
// y = (sum_{n=0..20} F^n x / n!) * exp(lerp(mc[...,0]))
// F: xn[t] = sum_{d=1..49} lerp_t(mc[:, :, d]) * xa[t-d]
//
// Single fused kernel: each block owns (b, tile) with a 1024-sample left halo
// (>= 20 stages * 49 lag = 980). All 20 stages run in LDS ping-pong buffers.
// Taps are frame-piecewise-linear -> factor into two fixed-tap dot products
// per thread (taps in registers, loaded once, reused across all 20 stages).

#define FO    49      // filter order (lags 1..49)
#define FP    80      // frame period
#define NST   20      // Taylor stages
#define NB    8       // batch
#define TT    160000  // samples per batch row
#define NFR   2000    // frames
#define NC    50      // coeffs per frame
#define HALO  1024    // left halo (multiple of 16, >= 980)
#define TOUT  5120    // outputs per tile (multiple of 80)
#define EE    6144    // extended region = HALO + TOUT
#define NT    384     // threads per block
#define RPT   16      // samples per thread (frame-aligned since 16 | 80)
#define PADW  64      // zero pad words in front of LDS buffer (window underrun)
#define TILES 32      // ceil(TT / TOUT) -> exactly 256 blocks

// 16B-group XOR swizzle: breaks the 64B lane stride (would be ~32-way bank
// conflict) into uniform 8 words/bank = LDS datapath minimum.
__device__ __forceinline__ int swz(int g) { return g ^ ((g >> 3) & 7); }

__global__ __launch_bounds__(NT, 2) void mlsa_kernel(
    const float* __restrict__ x, const float* __restrict__ mc,
    float* __restrict__ out) {
  __shared__ __align__(16) float buf[2][PADW + EE];
  const int tid  = threadIdx.x;
  const int b    = blockIdx.x >> 5;   // TILES == 32
  const int tile = blockIdx.x & 31;
  const int out0 = tile * TOUT;
  const int base = out0 - HALO;       // global sample index of local 0
  const float* __restrict__ xb  = x + b * TT;
  const float* __restrict__ mcb = mc + b * NFR * NC;

  // Zero the pad words (left-edge windows read them; must be 0 so tile 0
  // reproduces the reference's zero left-padding exactly).
  if (tid < PADW) { buf[0][tid] = 0.f; buf[1][tid] = 0.f; }

  // Stage x tile into buf[0] (swizzled 16B groups, coalesced global reads).
  #pragma unroll
  for (int i = 0; i < EE / 4 / NT; ++i) {
    int q  = i * NT + tid;      // data group index, 0..EE/4-1
    int t0 = base + q * 4;
    float4 v;
    v.x = (t0     >= 0 && t0     < TT) ? xb[t0]     : 0.f;
    v.y = (t0 + 1 >= 0 && t0 + 1 < TT) ? xb[t0 + 1] : 0.f;
    v.z = (t0 + 2 >= 0 && t0 + 2 < TT) ? xb[t0 + 2] : 0.f;
    v.w = (t0 + 3 >= 0 && t0 + 3 < TT) ? xb[t0 + 3] : 0.f;
    *(float4*)&buf[0][swz(q + PADW / 4) * 4] = v;
  }

  // Per-thread taps: this thread's 16 samples lie within ONE frame
  // (groups are 16-aligned, 16 | 80). Lerp: C_d(t) = tap0 + (p0+j)*tapd.
  const int g0 = base + tid * RPT;            // first sample (may be <0 / >=TT)
  const int gc = min(max(g0, 0), TT - 1);     // clamped (out-of-range threads
                                              // compute garbage, never stored;
                                              // t<0 windows are all-zero -> 0)
  const int n0  = gc / FP;
  const int n1  = min(n0 + 1, NFR - 1);       // replicate last frame
  const int p0i = gc - n0 * FP;
  const float* f0 = mcb + n0 * NC;
  const float* f1 = mcb + n1 * NC;
  float tap0[FO], tapd[FO];
  #pragma unroll
  for (int d = 1; d <= FO; ++d) {
    float a0 = f0[d];
    float a1 = f1[d];
    tap0[d - 1] = a0;
    tapd[d - 1] = (a1 - a0) * (1.0f / FP);
  }
  const float k0 = f0[0];
  const float k1 = f1[0];

  float y[RPT];
  __syncthreads();

  int cur = 0;
  const int gb = 4 * tid + 3;  // first 16B group of the 68-float window
  for (int s = 1; s <= NST; ++s) {
    // Window: A[i] = xa at local sample (16*tid - 52 + i); own samples at
    // A[52..67], lags reach back to A[3].
    float A[68];
    #pragma unroll
    for (int i = 0; i < 17; ++i) {
      float4 v = *(const float4*)&buf[cur][swz(gb + i) * 4];
      A[4 * i]     = v.x;
      A[4 * i + 1] = v.y;
      A[4 * i + 2] = v.z;
      A[4 * i + 3] = v.w;
    }
    if (s == 1) {  // y starts at x
      #pragma unroll
      for (int j = 0; j < RPT; ++j) y[j] = A[52 + j];
    }
    float acc0[RPT], acc1[RPT];
    #pragma unroll
    for (int j = 0; j < RPT; ++j) { acc0[j] = 0.f; acc1[j] = 0.f; }
    #pragma unroll
    for (int d = 1; d <= FO; ++d) {
      const float t0 = tap0[d - 1];
      const float t1 = tapd[d - 1];
      #pragma unroll
      for (int j = 0; j < RPT; ++j) {
        const float v = A[52 + j - d];
        acc0[j] = fmaf(t0, v, acc0[j]);
        acc1[j] = fmaf(t1, v, acc1[j]);
      }
    }
    const float inv_a = 1.0f / (float)s;
    float xn[RPT];
    #pragma unroll
    for (int j = 0; j < RPT; ++j) {
      xn[j] = fmaf((float)(p0i + j), acc1[j], acc0[j]) * inv_a;
      y[j] += xn[j];
    }
    const int wg = PADW / 4 + 4 * tid;  // thread's own 4 groups
    #pragma unroll
    for (int k = 0; k < 4; ++k) {
      float4 v;
      v.x = xn[4 * k];
      v.y = xn[4 * k + 1];
      v.z = xn[4 * k + 2];
      v.w = xn[4 * k + 3];
      *(float4*)&buf[cur ^ 1][swz(wg + k) * 4] = v;
    }
    __syncthreads();  // one barrier/stage: reads of cur are above, next
                      // stage's writes to cur are below this barrier
    cur ^= 1;
  }

  // Epilogue: out = y * exp(lerp(mc[...,0]))
  if (tid * RPT >= HALO && g0 < TT) {
    const float dk = (k1 - k0) * (1.0f / FP);
    float* ob = out + b * TT + g0;
    #pragma unroll
    for (int k = 0; k < 4; ++k) {
      float4 v;
      #pragma unroll
      for (int e = 0; e < 4; ++e) {
        const int j = 4 * k + e;
        const float K = __expf(fmaf((float)(p0i + j), dk, k0));
        ((float*)&v)[e] = y[j] * K;
      }
      *(float4*)&ob[4 * k] = v;
    }
  }
}

extern "C" void kernel_launch(void* const* d_in, const int* in_sizes, int n_in,
                              void* d_out, int out_size, void* d_ws, size_t ws_size,
                              hipStream_t stream) {
  const float* x  = (const float*)d_in[0];
  const float* mc = (const float*)d_in[1];
  float* out      = (float*)d_out;
  mlsa_kernel<<<NB * TILES, NT, 0, stream>>>(x, mc, out);
}

// Round 2
// 83.575 us; speedup vs baseline: 2.7262x; 2.7262x over previous
//
#include <hip/hip_runtime.h>

// MLSA-style multi-stage time-varying FIR.
// y = (sum_{n=0..20} F^n x / n!) * exp(lerp(mc[...,0]))
// F: xn[t] = sum_{d=1..49} lerp_t(mc[:, :, d]) * xa[t-d]
//
// Round-1 changes vs round-0 (which spilled ~100 VGPRs -> 251MB scratch fetch):
//  - taps moved from 98 registers/thread to a block-shared LDS table
//    taps[frame][d] = {c_d, (c_next_d - c_d)/80}, read per stage as float4
//    (2 lags per read, 400B row stride keeps 16B alignment).
//  - thread's own 16 samples kept in registers (xp) across stages; LDS window
//    read shrinks 17 -> 13 float4 groups.
//  - __launch_bounds__(NT, 1): grid == 256 == #CUs, 1 block/CU anyway; give
//    the allocator the full register file so nothing spills.

#define FO    49      // filter order (lags 1..49)
#define FP    80      // frame period
#define NST   20      // Taylor stages
#define NB    8       // batch
#define TT    160000  // samples per batch row
#define NFR   2000    // frames
#define NC    50      // coeffs per frame
#define HALO  1024    // left halo (multiple of 16, >= 20*49=980)
#define NT    384     // threads per block
#define RPT   16      // samples per thread (16 | 80 -> thread stays in 1 frame)
#define EE    6144    // NT*RPT extended region
#define TOUT  5120    // EE - HALO outputs per tile (multiple of 80)
#define TILES 32      // ceil(TT / TOUT)
#define PADW  64      // zero pad words in front of data (window underrun)
#define NFRL  79      // frames covered per block (77 n0 values + n1 + slack)
#define TROW  100     // tap row stride in words (49 float2 + pad; 400B, 16B-aligned)

// 16B-group XOR swizzle: breaks the power-of-2 lane stride bank pattern.
__device__ __forceinline__ int swz(int g) { return g ^ ((g >> 3) & 7); }

__global__ __launch_bounds__(NT, 1) void mlsa_kernel(
    const float* __restrict__ x, const float* __restrict__ mc,
    float* __restrict__ out) {
  __shared__ __align__(16) float sb0[PADW + EE];
  __shared__ __align__(16) float sb1[PADW + EE];
  __shared__ __align__(16) float taps[NFRL * TROW];

  const int tid  = threadIdx.x;
  const int b    = blockIdx.x >> 5;   // TILES == 32
  const int tile = blockIdx.x & 31;
  const int base = tile * TOUT - HALO;  // global sample index of local 0
  const float* __restrict__ xb  = x + b * TT;
  const float* __restrict__ mcb = mc + b * NFR * NC;

  // Zero the pad words (left-edge windows read them; must be 0 so tile 0
  // reproduces the reference's zero left-padding; for tile>0 they sit in the
  // "wrong anyway" cone below the halo).
  if (tid < PADW) { sb0[tid] = 0.f; sb1[tid] = 0.f; }

  // Stage x tile into sb0 (swizzled 16B groups, coalesced global reads).
  // base % 4 == 0 and TT % 4 == 0 -> a group is entirely in/out of range.
  #pragma unroll
  for (int i = 0; i < EE / 4 / NT; ++i) {
    const int q  = i * NT + tid;       // data group index 0..EE/4-1
    const int t0 = base + q * 4;
    float4 v = make_float4(0.f, 0.f, 0.f, 0.f);
    if (t0 >= 0 && t0 < TT) v = *(const float4*)(xb + t0);
    *(float4*)(sb0 + PADW + 4 * swz(q)) = v;
  }

  // Tap table -> LDS. Row e = frame fb+e (clamped); word 2*(d-1) holds
  // {c_d, (c_{f+1,d} - c_{f,d}) / FP}.
  const int fb = max(base, 0) / FP;
  for (int idx = tid; idx < NFRL * FO; idx += NT) {
    const int e  = idx / FO;
    const int dm = idx - e * FO;              // 0..48 -> lag d = dm+1
    const int fa = min(fb + e, NFR - 1);
    const int fn = min(fb + e + 1, NFR - 1);  // replicate last frame
    const float a0 = mcb[fa * NC + dm + 1];
    const float a1 = mcb[fn * NC + dm + 1];
    *(float2*)(taps + e * TROW + 2 * dm) = make_float2(a0, (a1 - a0) * (1.0f / FP));
  }

  // Per-thread sample geometry. Out-of-range threads (t<0 or t>=TT) see an
  // all-zero window -> xn == 0 regardless of (clamped) taps; never stored.
  const int g0 = base + tid * RPT;
  const int gc = min(max(g0, 0), TT - 1);
  const int n0 = gc / FP;
  const int fi = n0 - fb;
  const float p0f = (float)(gc - n0 * FP);

  // Own 16 samples from global; xp persists across stages (= prev stage xn).
  float xp[RPT];
  #pragma unroll
  for (int k = 0; k < 4; ++k) {
    const int t0 = g0 + 4 * k;
    float4 v = make_float4(0.f, 0.f, 0.f, 0.f);
    if (t0 >= 0 && t0 < TT) v = *(const float4*)(xb + t0);
    xp[4*k] = v.x; xp[4*k+1] = v.y; xp[4*k+2] = v.z; xp[4*k+3] = v.w;
  }
  float y[RPT];
  #pragma unroll
  for (int j = 0; j < RPT; ++j) y[j] = xp[j];

  const float* trow = taps + fi * TROW;
  __syncthreads();

  const float* rb = sb0;
  float*       wb = sb1;
  #pragma unroll 1
  for (int s = 1; s <= NST; ++s) {
    // A[k] = stage-(s-1) value at local sample 16*tid - 52 + k, k = 0..51
    // (lags 1..49 for j=0..15 need k in [3,51]; own j at xp[]).
    float A[52];
    #pragma unroll
    for (int i = 0; i < 13; ++i) {
      const int q = 4 * tid - 13 + i;
      const int w = (q < 0) ? (PADW + 4 * q) : (PADW + 4 * swz(q));
      const float4 v = *(const float4*)(rb + w);
      A[4*i] = v.x; A[4*i+1] = v.y; A[4*i+2] = v.z; A[4*i+3] = v.w;
    }
    float acc0[RPT], acc1[RPT];
    #pragma unroll
    for (int j = 0; j < RPT; ++j) { acc0[j] = 0.f; acc1[j] = 0.f; }
    #pragma unroll
    for (int p = 0; p < 25; ++p) {
      const float4 tp = *(const float4*)(trow + 4 * p);  // {c,dc} for d0 and d1
      const int d0 = 2 * p + 1;
      const int d1 = 2 * p + 2;
      #pragma unroll
      for (int j = 0; j < RPT; ++j) {
        const int ka = 52 + j - d0;   // compile-time constant
        const float v0 = (ka < 52) ? A[ka] : xp[ka - 52];
        acc0[j] = fmaf(tp.x, v0, acc0[j]);
        acc1[j] = fmaf(tp.y, v0, acc1[j]);
        if (d1 <= FO) {               // d1==50 slot is a dummy (skipped)
          const int kb = 52 + j - d1;
          const float v1 = (kb < 52) ? A[kb] : xp[kb - 52];
          acc0[j] = fmaf(tp.z, v1, acc0[j]);
          acc1[j] = fmaf(tp.w, v1, acc1[j]);
        }
      }
    }
    const float ia = 1.0f / (float)s;
    #pragma unroll
    for (int j = 0; j < RPT; ++j) {
      const float xn = fmaf(p0f + (float)j, acc1[j], acc0[j]) * ia;
      y[j] += xn;
      xp[j] = xn;
    }
    #pragma unroll
    for (int k = 0; k < 4; ++k) {
      float4 v;
      v.x = xp[4*k]; v.y = xp[4*k+1]; v.z = xp[4*k+2]; v.w = xp[4*k+3];
      *(float4*)(wb + PADW + 4 * swz(4 * tid + k)) = v;
    }
    __syncthreads();  // reads of rb above; conflicting writes next iter below
    const float* t = rb; rb = wb; wb = (float*)t;
  }

  // Epilogue: out = y * exp(lerp(mc[...,0]))
  if (tid >= HALO / RPT && g0 < TT) {
    const int n1 = min(n0 + 1, NFR - 1);
    const float k0 = mcb[n0 * NC];
    const float k1 = mcb[n1 * NC];
    const float dk = (k1 - k0) * (1.0f / FP);
    float* ob = out + b * TT + g0;
    #pragma unroll
    for (int k = 0; k < 4; ++k) {
      float4 v;
      #pragma unroll
      for (int e = 0; e < 4; ++e) {
        const int j = 4 * k + e;
        const float K = __expf(fmaf(p0f + (float)j, dk, k0));
        ((float*)&v)[e] = y[j] * K;
      }
      *(float4*)(ob + 4 * k) = v;
    }
  }
}

extern "C" void kernel_launch(void* const* d_in, const int* in_sizes, int n_in,
                              void* d_out, int out_size, void* d_ws, size_t ws_size,
                              hipStream_t stream) {
  const float* x  = (const float*)d_in[0];
  const float* mc = (const float*)d_in[1];
  float* out      = (float*)d_out;
  mlsa_kernel<<<NB * TILES, NT, 0, stream>>>(x, mc, out);
}

// Round 3
// 80.389 us; speedup vs baseline: 2.8342x; 1.0396x over previous
//
#include <hip/hip_runtime.h>

// MLSA-style multi-stage time-varying FIR.
// y = (sum_{n=0..20} F^n x / n!) * exp(lerp(mc[...,0]))
// F: xn[t] = sum_{d=1..49} lerp_t(mc[:, :, d]) * xa[t-d]
//
// Round-2 change: NT 384->768, RPT 16->8 (same tile EE=6144, same total FMA).
// Round-1 had 6 waves/CU (1 block of 384 on each of 256 CUs) -> VALUBusy 46%,
// issue starved by LDS latency on 1-wave SIMDs. 12 waves/CU (3/SIMD) hides it.

#define FO    49      // filter order (lags 1..49)
#define FP    80      // frame period
#define NST   20      // Taylor stages
#define NB    8       // batch
#define TT    160000  // samples per batch row
#define NFR   2000    // frames
#define NC    50      // coeffs per frame
#define HALO  1024    // left halo (multiple of RPT, >= 20*49=980)
#define NT    768     // threads per block (12 waves)
#define RPT   8       // samples per thread (8 | 80 -> thread stays in 1 frame)
#define EE    6144    // NT*RPT extended region
#define TOUT  5120    // EE - HALO outputs per tile (multiple of 16)
#define TILES 32      // TT / TOUT (exact: 32*5120 = 163840 covers 160000)
#define PADW  56      // zero pad words in front of data (window underrun: 52)
#define NFRL  78      // tap rows per block (<= 77 distinct n0 + 1 slack)
#define TROW  100     // tap row stride in words (49 float2 + pad; 400B)

// 16B-group XOR swizzle: spreads the 64B lane stride over all 8 bank quads.
__device__ __forceinline__ int swz(int g) { return g ^ ((g >> 3) & 7); }

__global__ __launch_bounds__(NT, 3) void mlsa_kernel(
    const float* __restrict__ x, const float* __restrict__ mc,
    float* __restrict__ out) {
  __shared__ __align__(16) float sb0[PADW + EE];
  __shared__ __align__(16) float sb1[PADW + EE];
  __shared__ __align__(16) float taps[NFRL * TROW];

  const int tid  = threadIdx.x;
  const int b    = blockIdx.x >> 5;   // TILES == 32
  const int tile = blockIdx.x & 31;
  const int base = tile * TOUT - HALO;  // global sample index of local 0
  const float* __restrict__ xb  = x + b * TT;
  const float* __restrict__ mcb = mc + b * NFR * NC;

  // Zero the pad words (left-edge windows read them; must be 0 so tile 0
  // reproduces the reference's zero left-padding).
  if (tid < PADW) { sb0[tid] = 0.f; sb1[tid] = 0.f; }

  // Stage x tile into sb0 (swizzled 16B groups, coalesced global reads).
  // base % 4 == 0 and TT % 4 == 0 -> a group is entirely in/out of range.
  #pragma unroll
  for (int i = 0; i < EE / 4 / NT; ++i) {
    const int q  = i * NT + tid;       // data group index 0..EE/4-1
    const int t0 = base + q * 4;
    float4 v = make_float4(0.f, 0.f, 0.f, 0.f);
    if (t0 >= 0 && t0 < TT) v = *(const float4*)(xb + t0);
    *(float4*)(sb0 + PADW + 4 * swz(q)) = v;
  }

  // Tap table -> LDS. Row e = frame fb+e (clamped); word 2*(d-1) holds
  // {c_d, (c_{f+1,d} - c_{f,d}) / FP}.
  const int fb = max(base, 0) / FP;
  for (int idx = tid; idx < NFRL * FO; idx += NT) {
    const int e  = idx / FO;
    const int dm = idx - e * FO;              // 0..48 -> lag d = dm+1
    const int fa = min(fb + e, NFR - 1);
    const int fn = min(fb + e + 1, NFR - 1);  // replicate last frame
    const float a0 = mcb[fa * NC + dm + 1];
    const float a1 = mcb[fn * NC + dm + 1];
    *(float2*)(taps + e * TROW + 2 * dm) = make_float2(a0, (a1 - a0) * (1.0f / FP));
  }

  // Per-thread sample geometry. Out-of-range threads (t<0 or t>=TT) see an
  // all-zero window -> xn == 0 regardless of (clamped) taps; never stored.
  const int g0 = base + tid * RPT;
  const int gc = min(max(g0, 0), TT - 1);
  const int n0 = gc / FP;
  const int fi = n0 - fb;
  const float p0f = (float)(gc - n0 * FP);

  // Own 8 samples from global; xp persists across stages (= prev stage xn).
  float xp[RPT];
  #pragma unroll
  for (int k = 0; k < RPT / 4; ++k) {
    const int t0 = g0 + 4 * k;
    float4 v = make_float4(0.f, 0.f, 0.f, 0.f);
    if (t0 >= 0 && t0 < TT) v = *(const float4*)(xb + t0);
    xp[4*k] = v.x; xp[4*k+1] = v.y; xp[4*k+2] = v.z; xp[4*k+3] = v.w;
  }
  float y[RPT];
  #pragma unroll
  for (int j = 0; j < RPT; ++j) y[j] = xp[j];

  const float* trow = taps + fi * TROW;
  __syncthreads();

  const float* rb = sb0;
  float*       wb = sb1;
  #pragma unroll 1
  for (int s = 1; s <= NST; ++s) {
    // A[k] = stage-(s-1) value at local word 8*tid - 52 + k, k = 0..51
    // (lags 1..49 for j=0..7 need words 8t-49..8t-1; own j in xp[]).
    float A[52];
    #pragma unroll
    for (int i = 0; i < 13; ++i) {
      const int q = 2 * tid - 13 + i;
      const int w = (q < 0) ? (PADW + 4 * q) : (PADW + 4 * swz(q));
      const float4 v = *(const float4*)(rb + w);
      A[4*i] = v.x; A[4*i+1] = v.y; A[4*i+2] = v.z; A[4*i+3] = v.w;
    }
    float acc0[RPT], acc1[RPT];
    #pragma unroll
    for (int j = 0; j < RPT; ++j) { acc0[j] = 0.f; acc1[j] = 0.f; }
    #pragma unroll
    for (int p = 0; p < 25; ++p) {
      const float4 tp = *(const float4*)(trow + 4 * p);  // {c,dc} for d0,d1
      const int d0 = 2 * p + 1;
      const int d1 = 2 * p + 2;
      #pragma unroll
      for (int j = 0; j < RPT; ++j) {
        const int ka = 52 + j - d0;   // compile-time constant
        const float v0 = (ka < 52) ? A[ka] : xp[ka - 52];
        acc0[j] = fmaf(tp.x, v0, acc0[j]);
        acc1[j] = fmaf(tp.y, v0, acc1[j]);
        if (d1 <= FO) {               // d1==50 slot is a dummy (skipped)
          const int kb = 52 + j - d1;
          const float v1 = (kb < 52) ? A[kb] : xp[kb - 52];
          acc0[j] = fmaf(tp.z, v1, acc0[j]);
          acc1[j] = fmaf(tp.w, v1, acc1[j]);
        }
      }
    }
    const float ia = 1.0f / (float)s;
    #pragma unroll
    for (int j = 0; j < RPT; ++j) {
      const float xn = fmaf(p0f + (float)j, acc1[j], acc0[j]) * ia;
      y[j] += xn;
      xp[j] = xn;
    }
    #pragma unroll
    for (int k = 0; k < RPT / 4; ++k) {
      float4 v;
      v.x = xp[4*k]; v.y = xp[4*k+1]; v.z = xp[4*k+2]; v.w = xp[4*k+3];
      *(float4*)(wb + PADW + 4 * swz(2 * tid + k)) = v;
    }
    __syncthreads();  // reads of rb above; conflicting writes next iter below
    const float* t = rb; rb = wb; wb = (float*)t;
  }

  // Epilogue: out = y * exp(lerp(mc[...,0]))
  if (tid >= HALO / RPT && g0 < TT) {
    const int n1 = min(n0 + 1, NFR - 1);
    const float k0 = mcb[n0 * NC];
    const float k1 = mcb[n1 * NC];
    const float dk = (k1 - k0) * (1.0f / FP);
    float* ob = out + b * TT + g0;
    #pragma unroll
    for (int k = 0; k < RPT / 4; ++k) {
      float4 v;
      #pragma unroll
      for (int e = 0; e < 4; ++e) {
        const int j = 4 * k + e;
        const float K = __expf(fmaf(p0f + (float)j, dk, k0));
        ((float*)&v)[e] = y[j] * K;
      }
      *(float4*)(ob + 4 * k) = v;
    }
  }
}

extern "C" void kernel_launch(void* const* d_in, const int* in_sizes, int n_in,
                              void* d_out, int out_size, void* d_ws, size_t ws_size,
                              hipStream_t stream) {
  const float* x  = (const float*)d_in[0];
  const float* mc = (const float*)d_in[1];
  float* out      = (float*)d_out;
  mlsa_kernel<<<NB * TILES, NT, 0, stream>>>(x, mc, out);
}